// Round 5
// baseline (237.947 us; speedup 1.0000x reference)
//
#include <hip/hip_runtime.h>
#include <hip/hip_bf16.h>

#define TT 4096
#define CC 1024
#define NHEAD 16
#define DH 64
#define N3C 3072

typedef __attribute__((ext_vector_type(8))) short short8;
typedef __attribute__((ext_vector_type(4))) float floatx4;

// Q pre-scale: 1/sqrt(64) * log2(e)  (softmax in exp2 domain, m=0 fixed)
#define QSCALE 0.18033688011112042f

__device__ __forceinline__ short f2bf(float f) {
    union { __hip_bfloat16 h; short s; } u;
    u.h = __float2bfloat16(f);
    return u.s;
}

// async global->LDS 16B per lane; LDS dest = wave-uniform base + lane*16
__device__ __forceinline__ void gload_lds16(const void* g, void* l) {
    __builtin_amdgcn_global_load_lds(
        (const __attribute__((address_space(1))) unsigned int*)(unsigned long long)g,
        (__attribute__((address_space(3))) unsigned int*)(unsigned int)(unsigned long long)l,
        16, 0, 0);
}

// pack two fp32 -> bf16x2 by truncation (1 v_perm)
__device__ __forceinline__ unsigned pk_trunc(float lo, float hi) {
    return __builtin_amdgcn_perm(__float_as_uint(hi), __float_as_uint(lo), 0x07060302u);
}

// ---------------- fused prep: cvt x->bf16, transpose both weights ----------------
__device__ __forceinline__ void tr_body(const float* __restrict__ in, short* __restrict__ out,
                                        int K, int N, int bx, int by, int tid, float (*tile)[33]) {
    int nt = bx * 32, kt = by * 32;
    int tx = tid & 31, ty = tid >> 5;
#pragma unroll
    for (int i = 0; i < 32; i += 8)
        tile[ty + i][tx] = in[(size_t)(kt + ty + i) * N + nt + tx];
    __syncthreads();
#pragma unroll
    for (int i = 0; i < 32; i += 8)
        out[(size_t)(nt + ty + i) * K + kt + tx] = f2bf(tile[tx][ty + i]);
}

__global__ void k_prep(const float* __restrict__ x, short* __restrict__ xb,
                       const float* __restrict__ w_qkv, short* __restrict__ wqkvT,
                       const float* __restrict__ w_proj, short* __restrict__ wprojT) {
    __shared__ float tile[32][33];
    int id = blockIdx.x;
    int tid = threadIdx.x;
    if (id < 4096) {
        int i = (id * 256 + tid) * 4;
        float4 v = *(const float4*)&x[i];
        short4 r;
        r.x = f2bf(v.x); r.y = f2bf(v.y); r.z = f2bf(v.z); r.w = f2bf(v.w);
        *(short4*)&xb[i] = r;
    } else if (id < 4096 + 3072) {
        int r = id - 4096;
        tr_body(w_qkv, wqkvT, CC, N3C, r % 96, r / 96, tid, tile);
    } else {
        int r = id - 7168;
        tr_body(w_proj, wprojT, CC, CC, r & 31, r >> 5, tid, tile);
    }
}

// ---------------- GEMM1: qkv = x @ w_qkv + b  (BK=64, two [128][32] sub-buffers) ----
__global__ __launch_bounds__(256) void k_gemm_qkv(const short* __restrict__ A,
                                                  const short* __restrict__ Bt,
                                                  const float* __restrict__ bias,
                                                  short* __restrict__ Q,
                                                  short* __restrict__ Kb,
                                                  short* __restrict__ Vtg) {
    const int m0 = blockIdx.y * 128;
    const int n0 = blockIdx.x * 128;
    __shared__ __attribute__((aligned(16))) short As[2][128 * 32];
    __shared__ __attribute__((aligned(16))) short Bs[2][128 * 32];
    const int tid = threadIdx.x;
    const int lane = tid & 63;
    const int w = tid >> 6;
    const int wm = w >> 1, wn = w & 1;
    const int quad = lane >> 4;
    const int l16 = lane & 15;

    const int r0 = tid >> 2, c0 = (tid & 3) * 8;
    const short* pA[2][2]; const short* pB[2][2];
    short* lA[2][2]; short* lB[2][2];
#pragma unroll
    for (int it = 0; it < 2; ++it)
#pragma unroll
        for (int hh = 0; hh < 2; ++hh) {
            pA[it][hh] = A + (size_t)(m0 + it * 64 + r0) * CC + hh * 32 + c0;
            pB[it][hh] = Bt + (size_t)(n0 + it * 64 + r0) * CC + hh * 32 + c0;
            lA[it][hh] = &As[hh][(it * 256 + w * 64) * 8];
            lB[it][hh] = &Bs[hh][(it * 256 + w * 64) * 8];
        }

    floatx4 acc[4][4] = {};
    for (int kb = 0; kb < CC; kb += 64) {
        __syncthreads();
#pragma unroll
        for (int it = 0; it < 2; ++it)
#pragma unroll
            for (int hh = 0; hh < 2; ++hh) {
                gload_lds16(pA[it][hh] + kb, lA[it][hh]);
                gload_lds16(pB[it][hh] + kb, lB[it][hh]);
            }
        __syncthreads();
#pragma unroll
        for (int kk = 0; kk < 2; ++kk) {
            short8 af[4], bf[4];
#pragma unroll
            for (int mi = 0; mi < 4; ++mi)
                af[mi] = *(const short8*)&As[kk][(wm * 64 + mi * 16 + l16) * 32 + quad * 8];
#pragma unroll
            for (int ni = 0; ni < 4; ++ni)
                bf[ni] = *(const short8*)&Bs[kk][(wn * 64 + ni * 16 + l16) * 32 + quad * 8];
#pragma unroll
            for (int mi = 0; mi < 4; ++mi)
#pragma unroll
                for (int ni = 0; ni < 4; ++ni)
                    acc[mi][ni] = __builtin_amdgcn_mfma_f32_16x16x32_bf16(af[mi], bf[ni], acc[mi][ni], 0, 0, 0);
        }
    }
#pragma unroll
    for (int mi = 0; mi < 4; ++mi) {
#pragma unroll
        for (int ni = 0; ni < 4; ++ni) {
            int gm = m0 + wm * 64 + mi * 16 + quad * 4;
            int gn = n0 + wn * 64 + ni * 16 + l16;
            int which = gn >> 10;
            int cc = gn & 1023;
            int h = cc >> 6, d = cc & 63;
            float bv = bias[gn];
            if (which == 0) {
#pragma unroll
                for (int r = 0; r < 4; ++r) {
                    float v = (acc[mi][ni][r] + bv) * QSCALE;
                    Q[((size_t)h * TT + (gm + r)) * DH + d] = f2bf(v);
                }
            } else if (which == 1) {
#pragma unroll
                for (int r = 0; r < 4; ++r) {
                    float v = acc[mi][ni][r] + bv;
                    Kb[((size_t)h * TT + (gm + r)) * DH + d] = f2bf(v);
                }
            } else {
                short4 vv;
                vv.x = f2bf(acc[mi][ni][0] + bv);
                vv.y = f2bf(acc[mi][ni][1] + bv);
                vv.z = f2bf(acc[mi][ni][2] + bv);
                vv.w = f2bf(acc[mi][ni][3] + bv);
                *(short4*)&Vtg[((size_t)h * DH + d) * TT + gm] = vv;
            }
        }
    }
}

// ---------------- flash attention v4: barrier-free wave-local strips ----------------
// Wave w owns k-strips k0 = c*128 + w*32. Per strip: S^T(K A-op, Q B-op) -> exp2 ->
// pack -> private-LDS transpose (rotated conflict-free layout) -> PV partial
// O[64q][64d] + L via ones-MFMA. No __syncthreads in the k-loop. Cross-wave
// reduction of (O,L) once per half via 2-phase LDS tree.
__global__ __launch_bounds__(256, 2) void k_attn(const short* __restrict__ Qh,
                                                 const short* __restrict__ Kh,
                                                 const short* __restrict__ VhT,
                                                 short* __restrict__ Ob) {
    const int h = blockIdx.x;
    const int pair = blockIdx.y;    // 0..31
    const int tid = threadIdx.x, lane = tid & 63, w = tid >> 6;
    const int quad = lane >> 4, l16 = lane & 15;

    // per-wave private P region: 8 blocks (mi*4+qg) x 64 slots x 8 B = 4 KB
    __shared__ __attribute__((aligned(16))) short Pws[4][2048];
    // reduction buffer: [wave][qg-in-phase][slot 0..3 = dg, 4 = L][64 lanes x 4 f]
    __shared__ __attribute__((aligned(16))) float Red[4][2][5][256];

    const short* Qp = Qh + (size_t)h * TT * DH;
    const short* Kp = Kh + (size_t)h * TT * DH;
    const short* Vp = VhT + (size_t)h * DH * TT;
    short* Pw = &Pws[w][0];

    // LDS transpose offsets (in 8-B slots)
    const int wslot = quad * 16 + ((l16 + quad * 4) & 15);           // write
    const int qcA = (quad & 1) * 2, qcB = qcA + 1;
    const int rslotA = qcA * 16 + ((l16 + qcA * 4) & 15);            // read lo
    const int rslotB = qcB * 16 + ((l16 + qcB * 4) & 15);            // read hi
    const int mi_r = quad >> 1;

    short8 onesB;
#pragma unroll
    for (int j = 0; j < 8; ++j) onesB[j] = (short)0x3F80;  // bf16 1.0

#pragma unroll 1
    for (int half = 0; half < 2; ++half) {
        const int qi = half ? (63 - pair) : pair;
        const int q0 = qi * 64;
        const int qmax = q0 + 63;

        short8 aq[4][2];
#pragma unroll
        for (int qg = 0; qg < 4; ++qg)
#pragma unroll
            for (int s = 0; s < 2; ++s)
                aq[qg][s] = *(const short8*)&Qp[(size_t)(q0 + qg * 16 + l16) * DH + s * 32 + quad * 8];

        floatx4 accO[4][4] = {};   // [qg][dg]
        floatx4 accL[4] = {};      // [qg]

        auto strip = [&](int k0, bool masked) {
            // V fragments (B-op of PV): V[k=k0+quad*8..+8][d=dg*16+l16]
            short8 vf[4];
#pragma unroll
            for (int dg = 0; dg < 4; ++dg)
                vf[dg] = *(const short8*)&Vp[(size_t)(dg * 16 + l16) * TT + k0 + quad * 8];
            // K fragments (A-op of S^T): K[k=k0+mi*16+l16][d=s*32+quad*8..+8]
            short8 kf[2][2];
#pragma unroll
            for (int mi = 0; mi < 2; ++mi)
#pragma unroll
                for (int s = 0; s < 2; ++s)
                    kf[mi][s] = *(const short8*)&Kp[(size_t)(k0 + mi * 16 + l16) * DH + s * 32 + quad * 8];

            // S^T: D[k][q], lane: k = mi*16+quad*4+r, q = qg*16+l16
            floatx4 accS[2][4] = {};
#pragma unroll
            for (int mi = 0; mi < 2; ++mi)
#pragma unroll
                for (int s = 0; s < 2; ++s)
#pragma unroll
                    for (int qg = 0; qg < 4; ++qg)
                        accS[mi][qg] = __builtin_amdgcn_mfma_f32_16x16x32_bf16(kf[mi][s], aq[qg][s], accS[mi][qg], 0, 0, 0);

            // exp2 (+ mask on diagonal strip), pack, write private LDS
            const int kq = k0 - q0 + quad * 4;
#pragma unroll
            for (int mi = 0; mi < 2; ++mi) {
#pragma unroll
                for (int qg = 0; qg < 4; ++qg) {
                    float p[4];
#pragma unroll
                    for (int r = 0; r < 4; ++r) {
                        float e = __builtin_amdgcn_exp2f(accS[mi][qg][r]);
                        if (masked)
                            e = (kq + mi * 16 + r <= qg * 16 + l16) ? e : 0.f;
                        p[r] = e;
                    }
                    uint2 pk;
                    pk.x = pk_trunc(p[0], p[1]);
                    pk.y = pk_trunc(p[2], p[3]);
                    *(uint2*)&Pw[((mi * 4 + qg) * 64 + wslot) * 4] = pk;
                }
            }
            // read back A-frags (own region; lgkm ordering only, no barrier)
#pragma unroll
            for (int qg = 0; qg < 4; ++qg) {
                const int blk = (mi_r * 4 + qg) * 64;
                union { uint4 u; short8 s; } af;
                *(uint2*)&af.u.x = *(const uint2*)&Pw[(blk + rslotA) * 4];
                *(uint2*)&af.u.z = *(const uint2*)&Pw[(blk + rslotB) * 4];
#pragma unroll
                for (int dg = 0; dg < 4; ++dg)
                    accO[qg][dg] = __builtin_amdgcn_mfma_f32_16x16x32_bf16(af.s, vf[dg], accO[qg][dg], 0, 0, 0);
                accL[qg] = __builtin_amdgcn_mfma_f32_16x16x32_bf16(af.s, onesB, accL[qg], 0, 0, 0);
            }
        };

        // full strips: k0 + 31 <= q0 - 1  (k0 <= q0-32)
        int tmp = q0 - 32 - w * 32;
        int nfull = (tmp >= 0) ? ((tmp >> 7) + 1) : 0;
        for (int c = 0; c < nfull; ++c) strip(c * 128 + w * 32, false);
        int k0d = nfull * 128 + w * 32;
        if (k0d <= qmax) strip(k0d, true);

        // ---- cross-wave (O, L) reduction + store, 2 phases of 2 qg ----
#pragma unroll 1
        for (int ph = 0; ph < 2; ++ph) {
            __syncthreads();   // buffer free (prev phase/half reads done)
#pragma unroll
            for (int g = 0; g < 2; ++g) {
                int qg = ph * 2 + g;
#pragma unroll
                for (int dg = 0; dg < 4; ++dg)
                    *(floatx4*)&Red[w][g][dg][lane * 4] = accO[qg][dg];
                *(floatx4*)&Red[w][g][4][lane * 4] = accL[qg];
            }
            __syncthreads();
#pragma unroll
            for (int g = 0; g < 2; ++g) {
                int qg = ph * 2 + g;
                floatx4 os = {}, ls = {};
#pragma unroll
                for (int sw = 0; sw < 4; ++sw) {
                    floatx4 o = *(const floatx4*)&Red[sw][g][w][lane * 4];
                    floatx4 l = *(const floatx4*)&Red[sw][g][4][lane * 4];
                    os += o; ls += l;
                }
#pragma unroll
                for (int r = 0; r < 4; ++r) {
                    int q = qg * 16 + quad * 4 + r;
                    float o = os[r] / ls[r];
                    Ob[(size_t)(q0 + q) * CC + h * DH + w * 16 + l16] = f2bf(o);
                }
            }
        }
    }
}

// ---------------- GEMM2: out = Ob @ w_proj + b (fp32 out, BK=64) ----------------
__global__ __launch_bounds__(256) void k_gemm_proj(const short* __restrict__ A,
                                                   const short* __restrict__ Bt,
                                                   const float* __restrict__ bias,
                                                   float* __restrict__ out) {
    const int m0 = blockIdx.y * 128;
    const int n0 = blockIdx.x * 128;
    __shared__ __attribute__((aligned(16))) short As[2][128 * 32];
    __shared__ __attribute__((aligned(16))) short Bs[2][128 * 32];
    const int tid = threadIdx.x;
    const int lane = tid & 63;
    const int w = tid >> 6;
    const int wm = w >> 1, wn = w & 1;
    const int quad = lane >> 4;
    const int l16 = lane & 15;

    const int r0 = tid >> 2, c0 = (tid & 3) * 8;
    const short* pA[2][2]; const short* pB[2][2];
    short* lA[2][2]; short* lB[2][2];
#pragma unroll
    for (int it = 0; it < 2; ++it)
#pragma unroll
        for (int hh = 0; hh < 2; ++hh) {
            pA[it][hh] = A + (size_t)(m0 + it * 64 + r0) * CC + hh * 32 + c0;
            pB[it][hh] = Bt + (size_t)(n0 + it * 64 + r0) * CC + hh * 32 + c0;
            lA[it][hh] = &As[hh][(it * 256 + w * 64) * 8];
            lB[it][hh] = &Bs[hh][(it * 256 + w * 64) * 8];
        }

    floatx4 acc[4][4] = {};
    for (int kb = 0; kb < CC; kb += 64) {
        __syncthreads();
#pragma unroll
        for (int it = 0; it < 2; ++it)
#pragma unroll
            for (int hh = 0; hh < 2; ++hh) {
                gload_lds16(pA[it][hh] + kb, lA[it][hh]);
                gload_lds16(pB[it][hh] + kb, lB[it][hh]);
            }
        __syncthreads();
#pragma unroll
        for (int kk = 0; kk < 2; ++kk) {
            short8 af[4], bf[4];
#pragma unroll
            for (int mi = 0; mi < 4; ++mi)
                af[mi] = *(const short8*)&As[kk][(wm * 64 + mi * 16 + l16) * 32 + quad * 8];
#pragma unroll
            for (int ni = 0; ni < 4; ++ni)
                bf[ni] = *(const short8*)&Bs[kk][(wn * 64 + ni * 16 + l16) * 32 + quad * 8];
#pragma unroll
            for (int mi = 0; mi < 4; ++mi)
#pragma unroll
                for (int ni = 0; ni < 4; ++ni)
                    acc[mi][ni] = __builtin_amdgcn_mfma_f32_16x16x32_bf16(af[mi], bf[ni], acc[mi][ni], 0, 0, 0);
        }
    }
#pragma unroll
    for (int mi = 0; mi < 4; ++mi) {
#pragma unroll
        for (int ni = 0; ni < 4; ++ni) {
            int gm = m0 + wm * 64 + mi * 16 + quad * 4;
            int gn = n0 + wn * 64 + ni * 16 + l16;
            float bv = bias[gn];
#pragma unroll
            for (int r = 0; r < 4; ++r)
                out[(size_t)(gm + r) * CC + gn] = acc[mi][ni][r] + bv;
        }
    }
}

extern "C" void kernel_launch(void* const* d_in, const int* in_sizes, int n_in,
                              void* d_out, int out_size, void* d_ws, size_t ws_size,
                              hipStream_t stream) {
    const float* x      = (const float*)d_in[0];
    const float* w_qkv  = (const float*)d_in[1];
    const float* b_qkv  = (const float*)d_in[2];
    const float* w_proj = (const float*)d_in[3];
    const float* b_proj = (const float*)d_in[4];
    float* out = (float*)d_out;
    char* ws = (char*)d_ws;

    short* xb     = (short*)(ws);                       // 8388608 B
    short* wqkvT  = (short*)(ws + 8388608);             // 6291456 B
    short* wprojT = (short*)(ws + 14680064);            // 2097152 B
    short* Qh     = (short*)(ws + 16777216);            // 8388608 B
    short* Kh     = (short*)(ws + 25165824);
    short* VhT    = (short*)(ws + 33554432);            // [H,64,T]
    short* Ob     = (short*)(ws + 41943040);
    // total 50331648 B (48 MB)

    k_prep<<<8192, 256, 0, stream>>>(x, xb, w_qkv, wqkvT, w_proj, wprojT);
    k_gemm_qkv<<<dim3(N3C / 128, TT / 128), 256, 0, stream>>>(xb, wqkvT, b_qkv, Qh, Kh, VhT);
    k_attn<<<dim3(NHEAD, 32), 256, 0, stream>>>(Qh, Kh, VhT, Ob);
    k_gemm_proj<<<dim3(CC / 128, TT / 128), 256, 0, stream>>>(Ob, wprojT, b_proj, out);
}

// Round 6
// 227.158 us; speedup vs baseline: 1.0475x; 1.0475x over previous
//
#include <hip/hip_runtime.h>
#include <hip/hip_bf16.h>

#define TT 4096
#define CC 1024
#define NHEAD 16
#define DH 64
#define N3C 3072

typedef __attribute__((ext_vector_type(8))) short short8;
typedef __attribute__((ext_vector_type(4))) float floatx4;

// Q pre-scale: 1/sqrt(64) * log2(e)  (softmax in exp2 domain, m=0 fixed)
#define QSCALE 0.18033688011112042f

__device__ __forceinline__ short f2bf(float f) {
    union { __hip_bfloat16 h; short s; } u;
    u.h = __float2bfloat16(f);
    return u.s;
}

// async global->LDS 16B per lane; LDS dest = wave-uniform base + lane*16
__device__ __forceinline__ void gload_lds16(const void* g, void* l) {
    __builtin_amdgcn_global_load_lds(
        (const __attribute__((address_space(1))) unsigned int*)(unsigned long long)g,
        (__attribute__((address_space(3))) unsigned int*)(unsigned int)(unsigned long long)l,
        16, 0, 0);
}

// pack two fp32 -> bf16x2 by truncation (1 v_perm)
__device__ __forceinline__ unsigned pk_trunc(float lo, float hi) {
    return __builtin_amdgcn_perm(__float_as_uint(hi), __float_as_uint(lo), 0x07060302u);
}

// ---------------- fused prep: cvt x->bf16, transpose both weights ----------------
__device__ __forceinline__ void tr_body(const float* __restrict__ in, short* __restrict__ out,
                                        int K, int N, int bx, int by, int tid, float (*tile)[33]) {
    int nt = bx * 32, kt = by * 32;
    int tx = tid & 31, ty = tid >> 5;
#pragma unroll
    for (int i = 0; i < 32; i += 8)
        tile[ty + i][tx] = in[(size_t)(kt + ty + i) * N + nt + tx];
    __syncthreads();
#pragma unroll
    for (int i = 0; i < 32; i += 8)
        out[(size_t)(nt + ty + i) * K + kt + tx] = f2bf(tile[tx][ty + i]);
}

__global__ void k_prep(const float* __restrict__ x, short* __restrict__ xb,
                       const float* __restrict__ w_qkv, short* __restrict__ wqkvT,
                       const float* __restrict__ w_proj, short* __restrict__ wprojT) {
    __shared__ float tile[32][33];
    int id = blockIdx.x;
    int tid = threadIdx.x;
    if (id < 4096) {
        int i = (id * 256 + tid) * 4;
        float4 v = *(const float4*)&x[i];
        short4 r;
        r.x = f2bf(v.x); r.y = f2bf(v.y); r.z = f2bf(v.z); r.w = f2bf(v.w);
        *(short4*)&xb[i] = r;
    } else if (id < 4096 + 3072) {
        int r = id - 4096;
        tr_body(w_qkv, wqkvT, CC, N3C, r % 96, r / 96, tid, tile);
    } else {
        int r = id - 7168;
        tr_body(w_proj, wprojT, CC, CC, r & 31, r >> 5, tid, tile);
    }
}

// ---------------- GEMM1: qkv = x @ w_qkv + b  (BK=64, two [128][32] sub-buffers) ----
__global__ __launch_bounds__(256) void k_gemm_qkv(const short* __restrict__ A,
                                                  const short* __restrict__ Bt,
                                                  const float* __restrict__ bias,
                                                  short* __restrict__ Q,
                                                  short* __restrict__ Kb,
                                                  short* __restrict__ Vtg) {
    const int m0 = blockIdx.y * 128;
    const int n0 = blockIdx.x * 128;
    __shared__ __attribute__((aligned(16))) short As[2][128 * 32];
    __shared__ __attribute__((aligned(16))) short Bs[2][128 * 32];
    const int tid = threadIdx.x;
    const int lane = tid & 63;
    const int w = tid >> 6;
    const int wm = w >> 1, wn = w & 1;
    const int quad = lane >> 4;
    const int l16 = lane & 15;

    const int r0 = tid >> 2, c0 = (tid & 3) * 8;
    const short* pA[2][2]; const short* pB[2][2];
    short* lA[2][2]; short* lB[2][2];
#pragma unroll
    for (int it = 0; it < 2; ++it)
#pragma unroll
        for (int hh = 0; hh < 2; ++hh) {
            pA[it][hh] = A + (size_t)(m0 + it * 64 + r0) * CC + hh * 32 + c0;
            pB[it][hh] = Bt + (size_t)(n0 + it * 64 + r0) * CC + hh * 32 + c0;
            lA[it][hh] = &As[hh][(it * 256 + w * 64) * 8];
            lB[it][hh] = &Bs[hh][(it * 256 + w * 64) * 8];
        }

    floatx4 acc[4][4] = {};
    for (int kb = 0; kb < CC; kb += 64) {
        __syncthreads();
#pragma unroll
        for (int it = 0; it < 2; ++it)
#pragma unroll
            for (int hh = 0; hh < 2; ++hh) {
                gload_lds16(pA[it][hh] + kb, lA[it][hh]);
                gload_lds16(pB[it][hh] + kb, lB[it][hh]);
            }
        __syncthreads();
#pragma unroll
        for (int kk = 0; kk < 2; ++kk) {
            short8 af[4], bf[4];
#pragma unroll
            for (int mi = 0; mi < 4; ++mi)
                af[mi] = *(const short8*)&As[kk][(wm * 64 + mi * 16 + l16) * 32 + quad * 8];
#pragma unroll
            for (int ni = 0; ni < 4; ++ni)
                bf[ni] = *(const short8*)&Bs[kk][(wn * 64 + ni * 16 + l16) * 32 + quad * 8];
#pragma unroll
            for (int mi = 0; mi < 4; ++mi)
#pragma unroll
                for (int ni = 0; ni < 4; ++ni)
                    acc[mi][ni] = __builtin_amdgcn_mfma_f32_16x16x32_bf16(af[mi], bf[ni], acc[mi][ni], 0, 0, 0);
        }
    }
#pragma unroll
    for (int mi = 0; mi < 4; ++mi) {
#pragma unroll
        for (int ni = 0; ni < 4; ++ni) {
            int gm = m0 + wm * 64 + mi * 16 + quad * 4;
            int gn = n0 + wn * 64 + ni * 16 + l16;
            int which = gn >> 10;
            int cc = gn & 1023;
            int h = cc >> 6, d = cc & 63;
            float bv = bias[gn];
            if (which == 0) {
#pragma unroll
                for (int r = 0; r < 4; ++r) {
                    float v = (acc[mi][ni][r] + bv) * QSCALE;
                    Q[((size_t)h * TT + (gm + r)) * DH + d] = f2bf(v);
                }
            } else if (which == 1) {
#pragma unroll
                for (int r = 0; r < 4; ++r) {
                    float v = acc[mi][ni][r] + bv;
                    Kb[((size_t)h * TT + (gm + r)) * DH + d] = f2bf(v);
                }
            } else {
                short4 vv;
                vv.x = f2bf(acc[mi][ni][0] + bv);
                vv.y = f2bf(acc[mi][ni][1] + bv);
                vv.z = f2bf(acc[mi][ni][2] + bv);
                vv.w = f2bf(acc[mi][ni][3] + bv);
                *(short4*)&Vtg[((size_t)h * DH + d) * TT + gm] = vv;
            }
        }
    }
}

// ---------------- flash attention v5: R3 structure, 1024-block heavy-first grid ----
// K & V fragments direct from global (no LDS staging); only P round-trips LDS.
// S^T k-strip per wave; PV d-strip per wave; Ps double-buffered -> 1 barrier/iter.
// grid (h, y): qi = 63-y (heavy blocks dispatch first); id%8 = h%8 pins heads
// to XCDs for K/V L2 residency. 4 blocks/CU resident (36 KB LDS, <=128 VGPR).
__global__ __launch_bounds__(256, 4) void k_attn(const short* __restrict__ Qh,
                                                 const short* __restrict__ Kh,
                                                 const short* __restrict__ VhT,
                                                 short* __restrict__ Ob) {
    const int h = blockIdx.x;
    const int qi = 63 - blockIdx.y;
    const int tid = threadIdx.x, lane = tid & 63, w = tid >> 6;
    const int quad = lane >> 4, l16 = lane & 15;

    __shared__ __attribute__((aligned(16))) short Ps[2][64 * 136];
    __shared__ float wl[4][64];
    __shared__ float lsum[64];

    const short* Qp = Qh + (size_t)h * TT * DH;
    const short* Kp = Kh + (size_t)h * TT * DH;
    const short* Vp = VhT + (size_t)h * DH * TT;

    const int q0 = qi * 64;
    const int nk = (qi >> 1) + 1;

    short8 aq[4][2];
#pragma unroll
    for (int qg = 0; qg < 4; ++qg)
#pragma unroll
        for (int s = 0; s < 2; ++s)
            aq[qg][s] = *(const short8*)&Qp[(size_t)(q0 + qg * 16 + l16) * DH + s * 32 + quad * 8];

    floatx4 accO[4] = {};
    float l_part[4] = {0.f, 0.f, 0.f, 0.f};
    int buf = 0;

    for (int ki = 0; ki < nk; ++ki) {
        const int k0 = ki * 128;
        const bool masked = (ki == nk - 1);

        // K fragments: wave's k-strip [k0+w*32, +32)
        short8 kf[2][2];
#pragma unroll
        for (int mi = 0; mi < 2; ++mi)
#pragma unroll
            for (int s = 0; s < 2; ++s)
                kf[mi][s] = *(const short8*)&Kp[(size_t)(k0 + w * 32 + mi * 16 + l16) * DH + s * 32 + quad * 8];

        // S^T strips: D[k][q], lane: k = w*32+mi*16+quad*4+r, q = qg*16+l16
        floatx4 accS[2][4] = {};
#pragma unroll
        for (int mi = 0; mi < 2; ++mi)
#pragma unroll
            for (int s = 0; s < 2; ++s)
#pragma unroll
                for (int qg = 0; qg < 4; ++qg)
                    accS[mi][qg] = __builtin_amdgcn_mfma_f32_16x16x32_bf16(kf[mi][s], aq[qg][s], accS[mi][qg], 0, 0, 0);

        // softmax (m=0, exp2 domain) + pack -> Ps
        short* Pb = &Ps[buf][0];
#pragma unroll
        for (int mi = 0; mi < 2; ++mi) {
            const int kbase = k0 + w * 32 + mi * 16 + quad * 4;
#pragma unroll
            for (int qg = 0; qg < 4; ++qg) {
                float p[4];
#pragma unroll
                for (int r = 0; r < 4; ++r) {
                    float e = __builtin_amdgcn_exp2f(accS[mi][qg][r]);
                    if (masked)
                        e = (kbase + r <= q0 + qg * 16 + l16) ? e : 0.f;
                    p[r] = e;
                    l_part[qg] += e;
                }
                uint2 pk;
                pk.x = pk_trunc(p[0], p[1]);
                pk.y = pk_trunc(p[2], p[3]);
                *(uint2*)&Pb[(qg * 16 + l16) * 136 + w * 32 + mi * 16 + quad * 4] = pk;
            }
        }

        // V fragments (d-strip [w*16,+16)) — issue before barrier to hide latency
        short8 vf[4];
#pragma unroll
        for (int ks = 0; ks < 4; ++ks)
            vf[ks] = *(const short8*)&Vp[(size_t)(w * 16 + l16) * TT + k0 + ks * 32 + quad * 8];

        __syncthreads();   // Ps[buf] visible

        // O[q][d-strip] += P V
#pragma unroll
        for (int qg = 0; qg < 4; ++qg)
#pragma unroll
            for (int ks = 0; ks < 4; ++ks) {
                short8 ap = *(const short8*)&Pb[(qg * 16 + l16) * 136 + ks * 32 + quad * 8];
                accO[qg] = __builtin_amdgcn_mfma_f32_16x16x32_bf16(ap, vf[ks], accO[qg], 0, 0, 0);
            }
        buf ^= 1;
    }

    // reduce l: lane holds partials for q = qg*16+l16 (over its 8 k-rows)
#pragma unroll
    for (int qg = 0; qg < 4; ++qg) {
        float lr = l_part[qg];
        lr += __shfl_xor(lr, 16, 64);
        lr += __shfl_xor(lr, 32, 64);
        if (lane < 16) wl[w][qg * 16 + lane] = lr;
    }
    __syncthreads();
    if (tid < 64) lsum[tid] = wl[0][tid] + wl[1][tid] + wl[2][tid] + wl[3][tid];
    __syncthreads();

    // epilogue: lane holds O[q = qg*16+quad*4+r][d = w*16+l16]
#pragma unroll
    for (int qg = 0; qg < 4; ++qg) {
#pragma unroll
        for (int r = 0; r < 4; ++r) {
            int q = qg * 16 + quad * 4 + r;
            float o = accO[qg][r] / lsum[q];
            Ob[(size_t)(q0 + q) * CC + h * DH + w * 16 + l16] = f2bf(o);
        }
    }
}

// ---------------- GEMM2: out = Ob @ w_proj + b (fp32 out, BK=64) ----------------
__global__ __launch_bounds__(256) void k_gemm_proj(const short* __restrict__ A,
                                                   const short* __restrict__ Bt,
                                                   const float* __restrict__ bias,
                                                   float* __restrict__ out) {
    const int m0 = blockIdx.y * 128;
    const int n0 = blockIdx.x * 128;
    __shared__ __attribute__((aligned(16))) short As[2][128 * 32];
    __shared__ __attribute__((aligned(16))) short Bs[2][128 * 32];
    const int tid = threadIdx.x;
    const int lane = tid & 63;
    const int w = tid >> 6;
    const int wm = w >> 1, wn = w & 1;
    const int quad = lane >> 4;
    const int l16 = lane & 15;

    const int r0 = tid >> 2, c0 = (tid & 3) * 8;
    const short* pA[2][2]; const short* pB[2][2];
    short* lA[2][2]; short* lB[2][2];
#pragma unroll
    for (int it = 0; it < 2; ++it)
#pragma unroll
        for (int hh = 0; hh < 2; ++hh) {
            pA[it][hh] = A + (size_t)(m0 + it * 64 + r0) * CC + hh * 32 + c0;
            pB[it][hh] = Bt + (size_t)(n0 + it * 64 + r0) * CC + hh * 32 + c0;
            lA[it][hh] = &As[hh][(it * 256 + w * 64) * 8];
            lB[it][hh] = &Bs[hh][(it * 256 + w * 64) * 8];
        }

    floatx4 acc[4][4] = {};
    for (int kb = 0; kb < CC; kb += 64) {
        __syncthreads();
#pragma unroll
        for (int it = 0; it < 2; ++it)
#pragma unroll
            for (int hh = 0; hh < 2; ++hh) {
                gload_lds16(pA[it][hh] + kb, lA[it][hh]);
                gload_lds16(pB[it][hh] + kb, lB[it][hh]);
            }
        __syncthreads();
#pragma unroll
        for (int kk = 0; kk < 2; ++kk) {
            short8 af[4], bf[4];
#pragma unroll
            for (int mi = 0; mi < 4; ++mi)
                af[mi] = *(const short8*)&As[kk][(wm * 64 + mi * 16 + l16) * 32 + quad * 8];
#pragma unroll
            for (int ni = 0; ni < 4; ++ni)
                bf[ni] = *(const short8*)&Bs[kk][(wn * 64 + ni * 16 + l16) * 32 + quad * 8];
#pragma unroll
            for (int mi = 0; mi < 4; ++mi)
#pragma unroll
                for (int ni = 0; ni < 4; ++ni)
                    acc[mi][ni] = __builtin_amdgcn_mfma_f32_16x16x32_bf16(af[mi], bf[ni], acc[mi][ni], 0, 0, 0);
        }
    }
#pragma unroll
    for (int mi = 0; mi < 4; ++mi) {
#pragma unroll
        for (int ni = 0; ni < 4; ++ni) {
            int gm = m0 + wm * 64 + mi * 16 + quad * 4;
            int gn = n0 + wn * 64 + ni * 16 + l16;
            float bv = bias[gn];
#pragma unroll
            for (int r = 0; r < 4; ++r)
                out[(size_t)(gm + r) * CC + gn] = acc[mi][ni][r] + bv;
        }
    }
}

extern "C" void kernel_launch(void* const* d_in, const int* in_sizes, int n_in,
                              void* d_out, int out_size, void* d_ws, size_t ws_size,
                              hipStream_t stream) {
    const float* x      = (const float*)d_in[0];
    const float* w_qkv  = (const float*)d_in[1];
    const float* b_qkv  = (const float*)d_in[2];
    const float* w_proj = (const float*)d_in[3];
    const float* b_proj = (const float*)d_in[4];
    float* out = (float*)d_out;
    char* ws = (char*)d_ws;

    short* xb     = (short*)(ws);                       // 8388608 B
    short* wqkvT  = (short*)(ws + 8388608);             // 6291456 B
    short* wprojT = (short*)(ws + 14680064);            // 2097152 B
    short* Qh     = (short*)(ws + 16777216);            // 8388608 B
    short* Kh     = (short*)(ws + 25165824);
    short* VhT    = (short*)(ws + 33554432);            // [H,64,T]
    short* Ob     = (short*)(ws + 41943040);
    // total 50331648 B (48 MB)

    k_prep<<<8192, 256, 0, stream>>>(x, xb, w_qkv, wqkvT, w_proj, wprojT);
    k_gemm_qkv<<<dim3(N3C / 128, TT / 128), 256, 0, stream>>>(xb, wqkvT, b_qkv, Qh, Kh, VhT);
    k_attn<<<dim3(NHEAD, 64), 256, 0, stream>>>(Qh, Kh, VhT, Ob);
    k_gemm_proj<<<dim3(CC / 128, TT / 128), 256, 0, stream>>>(Ob, wprojT, b_proj, out);
}

// Round 7
// 214.398 us; speedup vs baseline: 1.1098x; 1.0595x over previous
//
#include <hip/hip_runtime.h>
#include <hip/hip_bf16.h>

#define TT 4096
#define CC 1024
#define NHEAD 16
#define DH 64
#define N3C 3072

typedef __attribute__((ext_vector_type(8))) short short8;
typedef __attribute__((ext_vector_type(4))) float floatx4;

// Q pre-scale: 1/sqrt(64) * log2(e)  (softmax in exp2 domain, m=0 fixed)
#define QSCALE 0.18033688011112042f

__device__ __forceinline__ short f2bf(float f) {
    union { __hip_bfloat16 h; short s; } u;
    u.h = __float2bfloat16(f);
    return u.s;
}

// async global->LDS 16B per lane; LDS dest = wave-uniform base + lane*16
__device__ __forceinline__ void gload_lds16(const void* g, void* l) {
    __builtin_amdgcn_global_load_lds(
        (const __attribute__((address_space(1))) unsigned int*)(unsigned long long)g,
        (__attribute__((address_space(3))) unsigned int*)(unsigned int)(unsigned long long)l,
        16, 0, 0);
}

// pack two fp32 -> bf16x2 by truncation (1 v_perm)
__device__ __forceinline__ unsigned pk_trunc(float lo, float hi) {
    return __builtin_amdgcn_perm(__float_as_uint(hi), __float_as_uint(lo), 0x07060302u);
}

// ---------------- fused prep: cvt x->bf16, transpose both weights ----------------
__device__ __forceinline__ void tr_body(const float* __restrict__ in, short* __restrict__ out,
                                        int K, int N, int bx, int by, int tid, float (*tile)[33]) {
    int nt = bx * 32, kt = by * 32;
    int tx = tid & 31, ty = tid >> 5;
#pragma unroll
    for (int i = 0; i < 32; i += 8)
        tile[ty + i][tx] = in[(size_t)(kt + ty + i) * N + nt + tx];
    __syncthreads();
#pragma unroll
    for (int i = 0; i < 32; i += 8)
        out[(size_t)(nt + ty + i) * K + kt + tx] = f2bf(tile[tx][ty + i]);
}

__global__ void k_prep(const float* __restrict__ x, short* __restrict__ xb,
                       const float* __restrict__ w_qkv, short* __restrict__ wqkvT,
                       const float* __restrict__ w_proj, short* __restrict__ wprojT) {
    __shared__ float tile[32][33];
    int id = blockIdx.x;
    int tid = threadIdx.x;
    if (id < 4096) {
        int i = (id * 256 + tid) * 4;
        float4 v = *(const float4*)&x[i];
        short4 r;
        r.x = f2bf(v.x); r.y = f2bf(v.y); r.z = f2bf(v.z); r.w = f2bf(v.w);
        *(short4*)&xb[i] = r;
    } else if (id < 4096 + 3072) {
        int r = id - 4096;
        tr_body(w_qkv, wqkvT, CC, N3C, r % 96, r / 96, tid, tile);
    } else {
        int r = id - 7168;
        tr_body(w_proj, wprojT, CC, CC, r & 31, r >> 5, tid, tile);
    }
}

// ---------------- GEMM1: qkv = x @ w_qkv + b  (BK=64, two [128][32] sub-buffers) ----
__global__ __launch_bounds__(256) void k_gemm_qkv(const short* __restrict__ A,
                                                  const short* __restrict__ Bt,
                                                  const float* __restrict__ bias,
                                                  short* __restrict__ Q,
                                                  short* __restrict__ Kb,
                                                  short* __restrict__ Vtg) {
    const int m0 = blockIdx.y * 128;
    const int n0 = blockIdx.x * 128;
    __shared__ __attribute__((aligned(16))) short As[2][128 * 32];
    __shared__ __attribute__((aligned(16))) short Bs[2][128 * 32];
    const int tid = threadIdx.x;
    const int lane = tid & 63;
    const int w = tid >> 6;
    const int wm = w >> 1, wn = w & 1;
    const int quad = lane >> 4;
    const int l16 = lane & 15;

    const int r0 = tid >> 2, c0 = (tid & 3) * 8;
    const short* pA[2][2]; const short* pB[2][2];
    short* lA[2][2]; short* lB[2][2];
#pragma unroll
    for (int it = 0; it < 2; ++it)
#pragma unroll
        for (int hh = 0; hh < 2; ++hh) {
            pA[it][hh] = A + (size_t)(m0 + it * 64 + r0) * CC + hh * 32 + c0;
            pB[it][hh] = Bt + (size_t)(n0 + it * 64 + r0) * CC + hh * 32 + c0;
            lA[it][hh] = &As[hh][(it * 256 + w * 64) * 8];
            lB[it][hh] = &Bs[hh][(it * 256 + w * 64) * 8];
        }

    floatx4 acc[4][4] = {};
    for (int kb = 0; kb < CC; kb += 64) {
        __syncthreads();
#pragma unroll
        for (int it = 0; it < 2; ++it)
#pragma unroll
            for (int hh = 0; hh < 2; ++hh) {
                gload_lds16(pA[it][hh] + kb, lA[it][hh]);
                gload_lds16(pB[it][hh] + kb, lB[it][hh]);
            }
        __syncthreads();
#pragma unroll
        for (int kk = 0; kk < 2; ++kk) {
            short8 af[4], bf[4];
#pragma unroll
            for (int mi = 0; mi < 4; ++mi)
                af[mi] = *(const short8*)&As[kk][(wm * 64 + mi * 16 + l16) * 32 + quad * 8];
#pragma unroll
            for (int ni = 0; ni < 4; ++ni)
                bf[ni] = *(const short8*)&Bs[kk][(wn * 64 + ni * 16 + l16) * 32 + quad * 8];
#pragma unroll
            for (int mi = 0; mi < 4; ++mi)
#pragma unroll
                for (int ni = 0; ni < 4; ++ni)
                    acc[mi][ni] = __builtin_amdgcn_mfma_f32_16x16x32_bf16(af[mi], bf[ni], acc[mi][ni], 0, 0, 0);
        }
    }
#pragma unroll
    for (int mi = 0; mi < 4; ++mi) {
#pragma unroll
        for (int ni = 0; ni < 4; ++ni) {
            int gm = m0 + wm * 64 + mi * 16 + quad * 4;
            int gn = n0 + wn * 64 + ni * 16 + l16;
            int which = gn >> 10;
            int cc = gn & 1023;
            int h = cc >> 6, d = cc & 63;
            float bv = bias[gn];
            if (which == 0) {
#pragma unroll
                for (int r = 0; r < 4; ++r) {
                    float v = (acc[mi][ni][r] + bv) * QSCALE;
                    Q[((size_t)h * TT + (gm + r)) * DH + d] = f2bf(v);
                }
            } else if (which == 1) {
#pragma unroll
                for (int r = 0; r < 4; ++r) {
                    float v = acc[mi][ni][r] + bv;
                    Kb[((size_t)h * TT + (gm + r)) * DH + d] = f2bf(v);
                }
            } else {
                short4 vv;
                vv.x = f2bf(acc[mi][ni][0] + bv);
                vv.y = f2bf(acc[mi][ni][1] + bv);
                vv.z = f2bf(acc[mi][ni][2] + bv);
                vv.w = f2bf(acc[mi][ni][3] + bv);
                *(short4*)&Vtg[((size_t)h * DH + d) * TT + gm] = vv;
            }
        }
    }
}

// ---------------- flash attention v6: R3 body, 1024-block heavy-first grid ----
// K & V fragments direct from global (no LDS staging); only P round-trips LDS.
// S^T k-strip per wave; PV d-strip per wave; Ps double-buffered -> 1 barrier/iter.
// Plain __launch_bounds__(256): natural ~104 VGPR codegen (R5's (256,4) squeezed
// VGPR to 56 and regressed). 36 KB LDS + 104 VGPR -> 4 blocks/CU resident.
__global__ __launch_bounds__(256) void k_attn(const short* __restrict__ Qh,
                                              const short* __restrict__ Kh,
                                              const short* __restrict__ VhT,
                                              short* __restrict__ Ob) {
    const int h = blockIdx.x;
    const int qi = 63 - blockIdx.y;   // heavy blocks dispatch first
    const int tid = threadIdx.x, lane = tid & 63, w = tid >> 6;
    const int quad = lane >> 4, l16 = lane & 15;

    __shared__ __attribute__((aligned(16))) short Ps[2][64 * 136];
    __shared__ float wl[4][64];
    __shared__ float lsum[64];

    const short* Qp = Qh + (size_t)h * TT * DH;
    const short* Kp = Kh + (size_t)h * TT * DH;
    const short* Vp = VhT + (size_t)h * DH * TT;

    const int q0 = qi * 64;
    const int nk = (qi >> 1) + 1;

    short8 aq[4][2];
#pragma unroll
    for (int qg = 0; qg < 4; ++qg)
#pragma unroll
        for (int s = 0; s < 2; ++s)
            aq[qg][s] = *(const short8*)&Qp[(size_t)(q0 + qg * 16 + l16) * DH + s * 32 + quad * 8];

    floatx4 accO[4] = {};
    float l_part[4] = {0.f, 0.f, 0.f, 0.f};
    int buf = 0;

    for (int ki = 0; ki < nk; ++ki) {
        const int k0 = ki * 128;
        const bool masked = (ki == nk - 1);

        // K fragments: wave's k-strip [k0+w*32, +32)
        short8 kf[2][2];
#pragma unroll
        for (int mi = 0; mi < 2; ++mi)
#pragma unroll
            for (int s = 0; s < 2; ++s)
                kf[mi][s] = *(const short8*)&Kp[(size_t)(k0 + w * 32 + mi * 16 + l16) * DH + s * 32 + quad * 8];

        // S^T strips: D[k][q], lane: k = w*32+mi*16+quad*4+r, q = qg*16+l16
        floatx4 accS[2][4] = {};
#pragma unroll
        for (int mi = 0; mi < 2; ++mi)
#pragma unroll
            for (int s = 0; s < 2; ++s)
#pragma unroll
                for (int qg = 0; qg < 4; ++qg)
                    accS[mi][qg] = __builtin_amdgcn_mfma_f32_16x16x32_bf16(kf[mi][s], aq[qg][s], accS[mi][qg], 0, 0, 0);

        // softmax (m=0, exp2 domain) + pack -> Ps
        short* Pb = &Ps[buf][0];
#pragma unroll
        for (int mi = 0; mi < 2; ++mi) {
            const int kbase = k0 + w * 32 + mi * 16 + quad * 4;
#pragma unroll
            for (int qg = 0; qg < 4; ++qg) {
                float p[4];
#pragma unroll
                for (int r = 0; r < 4; ++r) {
                    float e = __builtin_amdgcn_exp2f(accS[mi][qg][r]);
                    if (masked)
                        e = (kbase + r <= q0 + qg * 16 + l16) ? e : 0.f;
                    p[r] = e;
                    l_part[qg] += e;
                }
                uint2 pk;
                pk.x = pk_trunc(p[0], p[1]);
                pk.y = pk_trunc(p[2], p[3]);
                *(uint2*)&Pb[(qg * 16 + l16) * 136 + w * 32 + mi * 16 + quad * 4] = pk;
            }
        }

        // V fragments (d-strip [w*16,+16)) — issue before barrier to hide latency
        short8 vf[4];
#pragma unroll
        for (int ks = 0; ks < 4; ++ks)
            vf[ks] = *(const short8*)&Vp[(size_t)(w * 16 + l16) * TT + k0 + ks * 32 + quad * 8];

        __syncthreads();   // Ps[buf] visible

        // O[q][d-strip] += P V
#pragma unroll
        for (int qg = 0; qg < 4; ++qg)
#pragma unroll
            for (int ks = 0; ks < 4; ++ks) {
                short8 ap = *(const short8*)&Pb[(qg * 16 + l16) * 136 + ks * 32 + quad * 8];
                accO[qg] = __builtin_amdgcn_mfma_f32_16x16x32_bf16(ap, vf[ks], accO[qg], 0, 0, 0);
            }
        buf ^= 1;
    }

    // reduce l: lane holds partials for q = qg*16+l16 (over its 8 k-rows)
#pragma unroll
    for (int qg = 0; qg < 4; ++qg) {
        float lr = l_part[qg];
        lr += __shfl_xor(lr, 16, 64);
        lr += __shfl_xor(lr, 32, 64);
        if (lane < 16) wl[w][qg * 16 + lane] = lr;
    }
    __syncthreads();
    if (tid < 64) lsum[tid] = wl[0][tid] + wl[1][tid] + wl[2][tid] + wl[3][tid];
    __syncthreads();

    // epilogue: lane holds O[q = qg*16+quad*4+r][d = w*16+l16]
#pragma unroll
    for (int qg = 0; qg < 4; ++qg) {
#pragma unroll
        for (int r = 0; r < 4; ++r) {
            int q = qg * 16 + quad * 4 + r;
            float o = accO[qg][r] / lsum[q];
            Ob[(size_t)(q0 + q) * CC + h * DH + w * 16 + l16] = f2bf(o);
        }
    }
}

// ---------------- GEMM2: out = Ob @ w_proj + b (fp32 out, BK=64) ----------------
__global__ __launch_bounds__(256) void k_gemm_proj(const short* __restrict__ A,
                                                   const short* __restrict__ Bt,
                                                   const float* __restrict__ bias,
                                                   float* __restrict__ out) {
    const int m0 = blockIdx.y * 128;
    const int n0 = blockIdx.x * 128;
    __shared__ __attribute__((aligned(16))) short As[2][128 * 32];
    __shared__ __attribute__((aligned(16))) short Bs[2][128 * 32];
    const int tid = threadIdx.x;
    const int lane = tid & 63;
    const int w = tid >> 6;
    const int wm = w >> 1, wn = w & 1;
    const int quad = lane >> 4;
    const int l16 = lane & 15;

    const int r0 = tid >> 2, c0 = (tid & 3) * 8;
    const short* pA[2][2]; const short* pB[2][2];
    short* lA[2][2]; short* lB[2][2];
#pragma unroll
    for (int it = 0; it < 2; ++it)
#pragma unroll
        for (int hh = 0; hh < 2; ++hh) {
            pA[it][hh] = A + (size_t)(m0 + it * 64 + r0) * CC + hh * 32 + c0;
            pB[it][hh] = Bt + (size_t)(n0 + it * 64 + r0) * CC + hh * 32 + c0;
            lA[it][hh] = &As[hh][(it * 256 + w * 64) * 8];
            lB[it][hh] = &Bs[hh][(it * 256 + w * 64) * 8];
        }

    floatx4 acc[4][4] = {};
    for (int kb = 0; kb < CC; kb += 64) {
        __syncthreads();
#pragma unroll
        for (int it = 0; it < 2; ++it)
#pragma unroll
            for (int hh = 0; hh < 2; ++hh) {
                gload_lds16(pA[it][hh] + kb, lA[it][hh]);
                gload_lds16(pB[it][hh] + kb, lB[it][hh]);
            }
        __syncthreads();
#pragma unroll
        for (int kk = 0; kk < 2; ++kk) {
            short8 af[4], bf[4];
#pragma unroll
            for (int mi = 0; mi < 4; ++mi)
                af[mi] = *(const short8*)&As[kk][(wm * 64 + mi * 16 + l16) * 32 + quad * 8];
#pragma unroll
            for (int ni = 0; ni < 4; ++ni)
                bf[ni] = *(const short8*)&Bs[kk][(wn * 64 + ni * 16 + l16) * 32 + quad * 8];
#pragma unroll
            for (int mi = 0; mi < 4; ++mi)
#pragma unroll
                for (int ni = 0; ni < 4; ++ni)
                    acc[mi][ni] = __builtin_amdgcn_mfma_f32_16x16x32_bf16(af[mi], bf[ni], acc[mi][ni], 0, 0, 0);
        }
    }
#pragma unroll
    for (int mi = 0; mi < 4; ++mi) {
#pragma unroll
        for (int ni = 0; ni < 4; ++ni) {
            int gm = m0 + wm * 64 + mi * 16 + quad * 4;
            int gn = n0 + wn * 64 + ni * 16 + l16;
            float bv = bias[gn];
#pragma unroll
            for (int r = 0; r < 4; ++r)
                out[(size_t)(gm + r) * CC + gn] = acc[mi][ni][r] + bv;
        }
    }
}

extern "C" void kernel_launch(void* const* d_in, const int* in_sizes, int n_in,
                              void* d_out, int out_size, void* d_ws, size_t ws_size,
                              hipStream_t stream) {
    const float* x      = (const float*)d_in[0];
    const float* w_qkv  = (const float*)d_in[1];
    const float* b_qkv  = (const float*)d_in[2];
    const float* w_proj = (const float*)d_in[3];
    const float* b_proj = (const float*)d_in[4];
    float* out = (float*)d_out;
    char* ws = (char*)d_ws;

    short* xb     = (short*)(ws);                       // 8388608 B
    short* wqkvT  = (short*)(ws + 8388608);             // 6291456 B
    short* wprojT = (short*)(ws + 14680064);            // 2097152 B
    short* Qh     = (short*)(ws + 16777216);            // 8388608 B
    short* Kh     = (short*)(ws + 25165824);
    short* VhT    = (short*)(ws + 33554432);            // [H,64,T]
    short* Ob     = (short*)(ws + 41943040);
    // total 50331648 B (48 MB)

    k_prep<<<8192, 256, 0, stream>>>(x, xb, w_qkv, wqkvT, w_proj, wprojT);
    k_gemm_qkv<<<dim3(N3C / 128, TT / 128), 256, 0, stream>>>(xb, wqkvT, b_qkv, Qh, Kh, VhT);
    k_attn<<<dim3(NHEAD, 64), 256, 0, stream>>>(Qh, Kh, VhT, Ob);
    k_gemm_proj<<<dim3(CC / 128, TT / 128), 256, 0, stream>>>(Ob, wprojT, b_proj, out);
}